// Round 10
// baseline (95.650 us; speedup 1.0000x reference)
//
#include <hip/hip_runtime.h>
#include <hip/hip_bf16.h>

typedef __bf16 bf16;
typedef __bf16 v8bf __attribute__((ext_vector_type(8)));
typedef __bf16 v4bf __attribute__((ext_vector_type(4)));
typedef float v4f __attribute__((ext_vector_type(4)));

#define HW 4096
#define CH 256
#define KC 32
#define RD 16
#define NB 2
#define BNEPS 1e-5f
#define VSTRIDE 4224
#define LOG2E 1.4426950408889634f

__device__ __forceinline__ float fexp2(float x) {
#if __has_builtin(__builtin_amdgcn_exp2f)
  return __builtin_amdgcn_exp2f(x);
#else
  return exp2f(x);
#endif
}
__device__ __forceinline__ float frcp(float x) {
#if __has_builtin(__builtin_amdgcn_rcpf)
  return __builtin_amdgcn_rcpf(x);
#else
  return 1.f / x;
#endif
}

// ---------------- workspace byte offsets (~44 MiB) ----------------
#define OFF_QT     0u          // bf16 [2][4096][32] (log2e folded via wall)
#define OFF_KT     524288u     // bf16 [2][4096][32]
#define OFF_BS1    1048576u    // bf16 [2][4096][32] pooled b1 (scaled -log2e*w_gb/9)
#define OFF_BS2    1572864u    // bf16 [2][4096][32] pooled b2
#define OFF_VT     2097152u    // bf16 [2][256][VSTRIDE] V transposed
#define OFF_B1R    6422528u    // bf16 [2][4096][32]
#define OFF_B2R    6946816u    // bf16 [2][4096][32]
#define OFF_PACC   7471104u    // bf16 [1024][64][256] split-K partial ctx
#define OFF_PL     41025536u   // f32 [1024*64]
#define OFF_WOBF   41287680u   // bf16 [256][256]
#define OFF_XBT    41418752u   // bf16 [2][4096][256]
#define OFF_WALL   45613056u   // bf16 [2][384][256]
#define OFF_MPART  46006272u   // f32 [2*256][64] per-tile channel partial sums

// ---------------- K1: transpose x -> bf16 [n][c]  + per-tile channel sums ----------
__global__ __launch_bounds__(256) void k_prep(const float* __restrict__ x,
    bf16* __restrict__ xbt, float* __restrict__ mpart) {
  __shared__ __align__(16) float ts[64][68];
  const int blk = blockIdx.x;               // 512
  const int b  = blk >> 8;
  const int id = blk & 255;
  const int ct = id >> 6, nt = id & 63;
  const int c0 = ct * 64, n0 = nt * 64;
  const int t = threadIdx.x;
  const int crow = t >> 2, nch = (t & 3) * 16;
  const float* xp = x + ((size_t)(b * CH + c0 + crow)) * HW + n0 + nch;
  #pragma unroll
  for (int i = 0; i < 4; ++i)
    *(v4f*)&ts[crow][nch + i * 4] = *(const v4f*)(xp + i * 4);
  __syncthreads();
  // per-channel partial sum over this tile's 64 n (deterministic: slot per tile)
  {
    float p = 0.f;
    #pragma unroll
    for (int j = 0; j < 16; ++j) p += ts[crow][nch + j];
    p += __shfl_xor(p, 1);
    p += __shfl_xor(p, 2);
    if ((t & 3) == 0) mpart[(size_t)(b * CH + c0 + crow) * 64 + nt] = p;
  }
  const int nl = t >> 2, cc0 = (t & 3) * 16;
  bf16* dst = xbt + ((size_t)(b * HW + n0 + nl)) * CH + c0 + cc0;
  v8bf o0, o1;
  #pragma unroll
  for (int j = 0; j < 8; ++j) { o0[j] = (bf16)ts[cc0 + j][nl]; o1[j] = (bf16)ts[cc0 + 8 + j][nl]; }
  *(v8bf*)dst = o0;
  *(v8bf*)(dst + 8) = o1;
}

// ---------------- K2: pack wall (gate inline) + convert Wo ----------------
__global__ __launch_bounds__(256) void k_pack(
    const float* __restrict__ mpart,
    const float* __restrict__ gw1, const float* __restrict__ gb1,
    const float* __restrict__ gw2, const float* __restrict__ gb2,
    const float* __restrict__ Wq, const float* __restrict__ Wk,
    const float* __restrict__ Wb1, const float* __restrict__ Wb2,
    const float* __restrict__ Wv, const float* __restrict__ Wo,
    bf16* __restrict__ wall, bf16* __restrict__ wo_bf) {
  __shared__ float ms[CH];
  __shared__ float hid[RD];
  const int blk = blockIdx.x;
  const int t = threadIdx.x;
  if (blk >= 768) {                          // Wo f32 -> bf16
    int i = (blk - 768) * 256 + t;
    wo_bf[i] = (bf16)Wo[i];
    return;
  }
  const int b = blk / 384, row = blk % 384;
  float v;
  if (row < 32)       v = Wq[row * CH + t] * LOG2E;
  else if (row < 64) {                       // gate-folded Wk (recompute MLP per block)
    float m = 0.f;
    const float* mp = mpart + (size_t)(b * CH + t) * 64;
    #pragma unroll
    for (int j = 0; j < 64; ++j) m += mp[j];
    ms[t] = m * (1.0f / HW);
    __syncthreads();
    if (t < RD) {
      float a = gb1[t];
      for (int c = 0; c < CH; ++c) a += gw1[t * CH + c] * ms[c];
      hid[t] = fmaxf(a, 0.f);
    }
    __syncthreads();
    float a = gb2[t];
    #pragma unroll
    for (int r = 0; r < RD; ++r) a += gw2[t * RD + r] * hid[r];
    float s = 1.f / (1.f + __expf(-a));
    v = Wk[(row - 32) * CH + t] * s;
  }
  else if (row < 96)  v = Wb1[(row - 64) * CH + t];
  else if (row < 128) v = Wb2[(row - 96) * CH + t];
  else                v = Wv[(row - 128) * CH + t];
  wall[((size_t)b * 384 + row) * CH + t] = (bf16)v;
}

// ---------------- K3: fused 1x1 projections via MFMA ----------------
__global__ __launch_bounds__(256, 4) void k_proj(
    const bf16* __restrict__ xbt, const bf16* __restrict__ wall,
    bf16* __restrict__ qt, bf16* __restrict__ kt,
    bf16* __restrict__ b1r, bf16* __restrict__ b2r, bf16* __restrict__ vt) {
  __shared__ __align__(16) bf16 xs[32][264];
  __shared__ __align__(16) bf16 tr[4][16][24];
  const int blk = blockIdx.x;
  const int b  = blk >> 9;
  const int bm = (blk >> 7) & 3;
  const int nt = blk & 127;
  const int n0 = nt * 32;
  const int t = threadIdx.x;
  {
    const int row = t >> 3, c0 = (t & 7) * 32;
    const bf16* src = xbt + ((size_t)(b * HW + n0 + row)) * CH + c0;
    #pragma unroll
    for (int i = 0; i < 4; ++i)
      *(v8bf*)&xs[row][c0 + i * 8] = *(const v8bf*)(src + i * 8);
  }
  __syncthreads();
  const int w = t >> 6, lane = t & 63, cl = lane & 15, kh = lane >> 4;
  const int nsub = (w & 1) * 16;
  const int otrio = (w >> 1) * 3;
  const v4f vzero = {0.f, 0.f, 0.f, 0.f};
  v4f acc[3] = {vzero, vzero, vzero};
  const bf16* wb = wall + ((size_t)b * 384 + bm * 96) * CH;
  for (int kk = 0; kk < 8; ++kk) {
    v8bf bx = *(const v8bf*)&xs[nsub + cl][kk * 32 + kh * 8];
    #pragma unroll
    for (int j = 0; j < 3; ++j) {
      v8bf af = *(const v8bf*)(wb + (size_t)((otrio + j) * 16 + cl) * CH + kk * 32 + kh * 8);
      acc[j] = __builtin_amdgcn_mfma_f32_16x16x32_bf16(af, bx, acc[j], 0, 0, 0);
    }
  }
  const int n = n0 + nsub + cl;
  #pragma unroll
  for (int j = 0; j < 3; ++j) {
    const int o0 = bm * 96 + (otrio + j) * 16;
    if (o0 < 128) {
      const bool rel = (o0 >= 64);
      v4bf pk;
      #pragma unroll
      for (int r = 0; r < 4; ++r) {
        float v = acc[j][r];
        if (rel) v = fmaxf(v, 0.f);
        pk[r] = (bf16)v;
      }
      const int seg = o0 >> 5;
      bf16* base = seg == 0 ? qt : seg == 1 ? kt : seg == 2 ? b1r : b2r;
      *(v4bf*)&base[((size_t)b * HW + n) * KC + (o0 & 31) + kh * 4] = pk;
    } else {
      #pragma unroll
      for (int r = 0; r < 4; ++r) tr[w][kh * 4 + r][cl] = (bf16)acc[j][r];
      asm volatile("s_waitcnt lgkmcnt(0)" ::: "memory");
      __builtin_amdgcn_sched_barrier(0);
      const int row = lane >> 2, nch = (lane & 3) * 4;
      v4bf d = *(const v4bf*)&tr[w][row][nch];
      *(v4bf*)&vt[((size_t)b * CH + (o0 - 128) + row) * VSTRIDE + n0 + nsub + nch] = d;
    }
  }
}

// ---------------- K3b: 1-D 3-tap pool (-log2e*w_gb/9 folded into bs1) ----------------
__global__ __launch_bounds__(256) void k_pool(const bf16* __restrict__ b1r,
    const bf16* __restrict__ b2r, const float* __restrict__ wgb,
    bf16* __restrict__ bs1, bf16* __restrict__ bs2) {
  int i = blockIdx.x * 256 + threadIdx.x;
  int n = (i >> 5) & (HW - 1);
  float a = (float)b1r[i], c = (float)b2r[i];
  if (n > 0)      { a += (float)b1r[i - KC]; c += (float)b2r[i - KC]; }
  if (n < HW - 1) { a += (float)b1r[i + KC]; c += (float)b2r[i + KC]; }
  const float ws = -LOG2E * wgb[0] * (1.f / 9.f);
  bs1[i] = (bf16)(a * ws);
  bs2[i] = (bf16)c;
}

// ---------------- K4: flash attention — KVBLK=32, 4 blocks/CU resident ----------------
// blk = rt*8 + os; 64-row tile, 512-key split, 16 steps of 32 keys.
// QK: wave w computes P rows [w*16,+16) (swapped MFMA, lane-local).
// PV: wave w computes all 64 rows x channels [w*64,+64).
// vbuf: 128 lines x 128B; 3-bit XOR swizzle slot3 = ((row&1)*4+slot)^(line&7) -> <=2-way.
__global__ __launch_bounds__(256, 4) void k_attn(
    const bf16* __restrict__ qtg, const bf16* __restrict__ ktg,
    const bf16* __restrict__ bs1g, const bf16* __restrict__ bs2g,
    const bf16* __restrict__ vtg,
    bf16* __restrict__ pacc, float* __restrict__ pl) {
  __shared__ __align__(16) bf16 vbuf[128][64];  // 16 KB: 256ch x 32keys
  __shared__ __align__(16) bf16 kbuf[32][40];   // K tile (single buffer, in-place)
  __shared__ __align__(16) bf16 bbuf[32][40];   // B2 tile
  __shared__ __align__(16) bf16 plds[64][40];   // P [qrow][key], 80B rows
  const int blk = blockIdx.x;
  const int rt  = blk >> 3;
  const int os  = blk & 7;
  const int b   = rt >> 6;
  const int row0 = (rt & 63) * 64;
  const int t = threadIdx.x;
  const int w = t >> 6;
  const int lane = t & 63;
  const int cl = lane & 15, kh = lane >> 4;
  const int kb = os * 512;
  const v4f vzero = {0.f, 0.f, 0.f, 0.f};
  const size_t qoff = ((size_t)(b * HW + row0 + w * 16 + cl)) * KC + kh * 8;
  const v8bf qf  = *(const v8bf*)(qtg + qoff);
  const v8bf b1f = *(const v8bf*)(bs1g + qoff);
  const bf16* kt = ktg + (size_t)b * HW * KC;
  const bf16* b2 = bs2g + (size_t)b * HW * KC;
  const bf16* vt = vtg + (size_t)b * CH * VSTRIDE;
  // K/B2 staging: threads 0-127 -> kbuf, 128-255 -> bbuf (1 v8bf each)
  const int sr = (t >> 2) & 31, sl = (t & 3) * 8;
  const bf16* sbase = (t < 128) ? kt : b2;
  bf16* sdst = (t < 128) ? &kbuf[sr][sl] : &bbuf[sr][sl];
  // V staging: instr i covers rows w*64+i*16+(l>>2), logical slot l&3
  const int vsl = lane & 3;
  const int vslot3 = ((((lane >> 2) & 1) * 4 + vsl) ^ (lane >> 3)) * 8;
  // V read: ch row = w*64+f*16+cl -> line w*32+f*8+(cl>>1), slot3 ((cl&1)*4+kh)^(cl>>1)
  const int rline = w * 32 + (cl >> 1);
  const int rslot = ((((cl & 1) * 4) + kh) ^ (cl >> 1)) * 8;

  *(v8bf*)sdst = *(const v8bf*)(sbase + (size_t)(kb + sr) * KC + sl);
  __syncthreads();

  v4f acc[16];
  #pragma unroll
  for (int f = 0; f < 16; ++f) acc[f] = vzero;
  float psum = 0.f;

  for (int s = 0; s < 16; ++s) {
    const int m0 = kb + s * 32;
    // V reg loads (consumed after QK)
    v8bf vr[4];
    #pragma unroll
    for (int i = 0; i < 4; ++i)
      vr[i] = *(const v8bf*)(vt + (size_t)(w * 64 + i * 16 + (lane >> 2)) * VSTRIDE + m0 + vsl * 8);
    // next K/B2 prefetch (consumed after PV)
    v8bf pr;
    if (s < 15)
      pr = *(const v8bf*)(sbase + (size_t)(m0 + 32 + sr) * KC + sl);
    // swapped QK: C[key][qrow]; lane owns 8 keys of its own row (w*16+cl)
    #pragma unroll
    for (int cb = 0; cb < 2; ++cb) {
      v8bf kf  = *(const v8bf*)&kbuf[cb * 16 + cl][kh * 8];
      v8bf b2f = *(const v8bf*)&bbuf[cb * 16 + cl][kh * 8];
      v4f sim = __builtin_amdgcn_mfma_f32_16x16x32_bf16(kf,  qf,  vzero, 0, 0, 0);
      v4f bia = __builtin_amdgcn_mfma_f32_16x16x32_bf16(b2f, b1f, vzero, 0, 0, 0);
      v4bf pk;
      #pragma unroll
      for (int r = 0; r < 4; ++r) {
        float bm = frcp(1.f + fexp2(bia[r]));   // sigmoid (-log2e folded in bs1)
        float pv = fexp2(sim[r] * bm);          // exp (log2e folded in qt)
        psum += pv;
        pk[r] = (bf16)pv;
      }
      *(v4bf*)&plds[w * 16 + cl][cb * 16 + kh * 4] = pk;
    }
    // stage V (swizzled)
    #pragma unroll
    for (int i = 0; i < 4; ++i)
      *(v8bf*)&vbuf[w * 32 + i * 8 + (lane >> 3)][vslot3] = vr[i];
    __syncthreads();                            // [A] P + V visible
    // PV: all 64 rows x my 64-ch slice
    v8bf vf[4], pa[4];
    #pragma unroll
    for (int f = 0; f < 4; ++f)
      vf[f] = *(const v8bf*)&vbuf[rline + f * 8][rslot];
    #pragma unroll
    for (int rg = 0; rg < 4; ++rg)
      pa[rg] = *(const v8bf*)&plds[rg * 16 + cl][kh * 8];
    #pragma unroll
    for (int rg = 0; rg < 4; ++rg)
      #pragma unroll
      for (int f = 0; f < 4; ++f)
        acc[rg * 4 + f] = __builtin_amdgcn_mfma_f32_16x16x32_bf16(pa[rg], vf[f], acc[rg * 4 + f], 0, 0, 0);
    // write next K/B2 in place (QK reads drained at [A])
    if (s < 15) *(v8bf*)sdst = pr;
    __syncthreads();                            // [B]
  }

  // ---- epilogue ----
  {
    float s2 = psum;
    s2 += __shfl_xor(s2, 16);
    s2 += __shfl_xor(s2, 32);
    if (kh == 0) pl[blk * 64 + w * 16 + cl] = s2;
  }
  // acc writeout via vbuf scratch (per-wave 16x64 slices; all PV reads done at final [B])
  bf16 (*ep)[64] = (bf16 (*)[64])vbuf;
  bf16* po = pacc + (size_t)blk * 64 * CH;
  for (int rg = 0; rg < 4; ++rg) {
    #pragma unroll
    for (int f = 0; f < 4; ++f)
      #pragma unroll
      for (int r = 0; r < 4; ++r)
        ep[w * 16 + kh * 4 + r][f * 16 + cl] = (bf16)acc[rg * 4 + f][r];
    asm volatile("s_waitcnt lgkmcnt(0)" ::: "memory");
    __builtin_amdgcn_sched_barrier(0);
    #pragma unroll
    for (int it = 0; it < 2; ++it) {
      int row = lane >> 2, chunk = it * 4 + (lane & 3);
      v8bf d = *(const v8bf*)&ep[w * 16 + row][chunk * 8];
      *(v8bf*)&po[(size_t)(rg * 16 + row) * CH + w * 64 + chunk * 8] = d;
    }
  }
}

// ---------------- K5: fused split-K combine + 1x1 conv + BN + ReLU + residual -------
__global__ __launch_bounds__(256) void k_outc(
    const bf16* __restrict__ pacc, const float* __restrict__ pl,
    const bf16* __restrict__ wo,
    const float* __restrict__ bns, const float* __restrict__ bnb,
    const float* __restrict__ bnm, const float* __restrict__ bnv,
    const float* __restrict__ gamma, const float* __restrict__ x,
    float* __restrict__ out) {
  const int blk = blockIdx.x;                  // 512
  const int n0g = blk * 16;
  const int b   = n0g >> 12;
  const int n0  = n0g & (HW - 1);
  const int t = threadIdx.x;
  const int w = t >> 6, lane = t & 63, cl = lane & 15, kh = lane >> 4;
  const int base = (blk >> 2) * 8;             // rt*8
  const int rl = (blk & 3) * 16 + cl;          // row within 64-row tile
  const v4f vzero = {0.f, 0.f, 0.f, 0.f};
  float den = 0.f;
  #pragma unroll
  for (int s = 0; s < 8; ++s) den += pl[(base + s) * 64 + rl];
  const float inv = 1.f / den;
  // build A-frags: sum 8 split partials in f32, normalize, pack bf16
  v8bf a[8];
  #pragma unroll
  for (int kk = 0; kk < 8; ++kk) {
    float sum[8] = {0.f, 0.f, 0.f, 0.f, 0.f, 0.f, 0.f, 0.f};
    #pragma unroll
    for (int s = 0; s < 8; ++s) {
      v8bf pv = *(const v8bf*)&pacc[((size_t)(base + s) * 64 + rl) * CH + kk * 32 + kh * 8];
      #pragma unroll
      for (int j = 0; j < 8; ++j) sum[j] += (float)pv[j];
    }
    #pragma unroll
    for (int j = 0; j < 8; ++j) a[kk][j] = (bf16)(sum[j] * inv);
  }
  v4f acc[4] = {vzero, vzero, vzero, vzero};
  #pragma unroll
  for (int kk = 0; kk < 8; ++kk)
    #pragma unroll
    for (int cg = 0; cg < 4; ++cg) {
      v8bf bfr = *(const v8bf*)(wo + (size_t)(w * 64 + cg * 16 + cl) * CH + kk * 32 + kh * 8);
      acc[cg] = __builtin_amdgcn_mfma_f32_16x16x32_bf16(a[kk], bfr, acc[cg], 0, 0, 0);
    }
  const float g = gamma[0];
  #pragma unroll
  for (int cg = 0; cg < 4; ++cg) {
    int o = w * 64 + cg * 16 + cl;
    float isc = bns[o] / sqrtf(bnv[o] + BNEPS);
    float mu = bnm[o], bb = bnb[o];
    size_t oi = ((size_t)b * CH + o) * HW + n0 + kh * 4;
    v4f xv = *(const v4f*)&x[oi];
    v4f ov;
    #pragma unroll
    for (int r = 0; r < 4; ++r) {
      float v = (acc[cg][r] - mu) * isc + bb;
      v = fmaxf(v, 0.f);
      ov[r] = g * v + xv[r];
    }
    *(v4f*)&out[oi] = ov;
  }
}

// ---------------- launch ----------------
extern "C" void kernel_launch(void* const* d_in, const int* in_sizes, int n_in,
                              void* d_out, int out_size, void* d_ws, size_t ws_size,
                              hipStream_t stream) {
  const float* x    = (const float*)d_in[0];
  const float* Wq   = (const float*)d_in[1];
  const float* Wk   = (const float*)d_in[2];
  const float* Wv   = (const float*)d_in[3];
  const float* Wb1  = (const float*)d_in[4];
  const float* Wb2  = (const float*)d_in[5];
  const float* wgb  = (const float*)d_in[6];
  const float* gw1  = (const float*)d_in[7];
  const float* gb1  = (const float*)d_in[8];
  const float* gw2  = (const float*)d_in[9];
  const float* gb2  = (const float*)d_in[10];
  const float* Wo   = (const float*)d_in[11];
  const float* bns  = (const float*)d_in[12];
  const float* bnb  = (const float*)d_in[13];
  const float* bnm  = (const float*)d_in[14];
  const float* bnv  = (const float*)d_in[15];
  const float* gam  = (const float*)d_in[16];

  char* ws = (char*)d_ws;
  bf16* qt    = (bf16*)(ws + OFF_QT);
  bf16* kt    = (bf16*)(ws + OFF_KT);
  bf16* bs1   = (bf16*)(ws + OFF_BS1);
  bf16* bs2   = (bf16*)(ws + OFF_BS2);
  bf16* vt    = (bf16*)(ws + OFF_VT);
  bf16* b1r   = (bf16*)(ws + OFF_B1R);
  bf16* b2r   = (bf16*)(ws + OFF_B2R);
  bf16* pacc  = (bf16*)(ws + OFF_PACC);
  float* plv  = (float*)(ws + OFF_PL);
  bf16* wobf  = (bf16*)(ws + OFF_WOBF);
  bf16* xbt   = (bf16*)(ws + OFF_XBT);
  bf16* wall  = (bf16*)(ws + OFF_WALL);
  float* mprt = (float*)(ws + OFF_MPART);
  float* out  = (float*)d_out;

  hipLaunchKernelGGL(k_prep, dim3(512),  dim3(256), 0, stream, x, xbt, mprt);
  hipLaunchKernelGGL(k_pack, dim3(1024), dim3(256), 0, stream, mprt, gw1, gb1, gw2, gb2,
                     Wq, Wk, Wb1, Wb2, Wv, Wo, wall, wobf);
  hipLaunchKernelGGL(k_proj, dim3(1024), dim3(256), 0, stream, xbt, wall, qt, kt, b1r, b2r, vt);
  hipLaunchKernelGGL(k_pool, dim3(NB * HW * KC / 256), dim3(256), 0, stream, b1r, b2r, wgb, bs1, bs2);
  hipLaunchKernelGGL(k_attn, dim3(1024), dim3(256), 0, stream, qt, kt, bs1, bs2, vt, pacc, plv);
  hipLaunchKernelGGL(k_outc, dim3(512),  dim3(256), 0, stream, pacc, plv, wobf, bns, bnb, bnm, bnv, gam, x, out);
}

// Round 11
// 88.194 us; speedup vs baseline: 1.0845x; 1.0845x over previous
//
#include <hip/hip_runtime.h>
#include <hip/hip_bf16.h>

typedef __bf16 bf16;
typedef __bf16 v8bf __attribute__((ext_vector_type(8)));
typedef __bf16 v4bf __attribute__((ext_vector_type(4)));
typedef float v4f __attribute__((ext_vector_type(4)));

#define HW 4096
#define CH 256
#define KC 32
#define RD 16
#define NB 2
#define BNEPS 1e-5f
#define VSTRIDE 4224
#define LOG2E 1.4426950408889634f

__device__ __forceinline__ float fexp2(float x) {
#if __has_builtin(__builtin_amdgcn_exp2f)
  return __builtin_amdgcn_exp2f(x);
#else
  return exp2f(x);
#endif
}
__device__ __forceinline__ float frcp(float x) {
#if __has_builtin(__builtin_amdgcn_rcpf)
  return __builtin_amdgcn_rcpf(x);
#else
  return 1.f / x;
#endif
}

// ---------------- workspace byte offsets (~44 MiB) ----------------
#define OFF_QT     0u          // bf16 [2][4096][32] (log2e folded via wall)
#define OFF_KT     524288u     // bf16 [2][4096][32]
#define OFF_BS1    1048576u    // bf16 [2][4096][32] pooled b1 (scaled -log2e*w_gb/9)
#define OFF_BS2    1572864u    // bf16 [2][4096][32] pooled b2
#define OFF_VT     2097152u    // bf16 [2][256][VSTRIDE] V transposed
#define OFF_B1R    6422528u    // bf16 [2][4096][32]
#define OFF_B2R    6946816u    // bf16 [2][4096][32]
#define OFF_PACC   7471104u    // bf16 [1024][64][256] split-K partial ctx
#define OFF_PL     41025536u   // f32 [1024*64]
#define OFF_WOBF   41287680u   // bf16 [256][256]
#define OFF_XBT    41418752u   // bf16 [2][4096][256]
#define OFF_WALL   45613056u   // bf16 [2][384][256]
#define OFF_MPART  46006272u   // f32 [2*256][64] per-tile channel partial sums

// ---------------- K1: transpose x -> bf16 [n][c]  + per-tile channel sums ----------
__global__ __launch_bounds__(256) void k_prep(const float* __restrict__ x,
    bf16* __restrict__ xbt, float* __restrict__ mpart) {
  __shared__ __align__(16) float ts[64][68];
  const int blk = blockIdx.x;               // 512
  const int b  = blk >> 8;
  const int id = blk & 255;
  const int ct = id >> 6, nt = id & 63;
  const int c0 = ct * 64, n0 = nt * 64;
  const int t = threadIdx.x;
  const int crow = t >> 2, nch = (t & 3) * 16;
  const float* xp = x + ((size_t)(b * CH + c0 + crow)) * HW + n0 + nch;
  #pragma unroll
  for (int i = 0; i < 4; ++i)
    *(v4f*)&ts[crow][nch + i * 4] = *(const v4f*)(xp + i * 4);
  __syncthreads();
  {
    float p = 0.f;
    #pragma unroll
    for (int j = 0; j < 16; ++j) p += ts[crow][nch + j];
    p += __shfl_xor(p, 1);
    p += __shfl_xor(p, 2);
    if ((t & 3) == 0) mpart[(size_t)(b * CH + c0 + crow) * 64 + nt] = p;
  }
  const int nl = t >> 2, cc0 = (t & 3) * 16;
  bf16* dst = xbt + ((size_t)(b * HW + n0 + nl)) * CH + c0 + cc0;
  v8bf o0, o1;
  #pragma unroll
  for (int j = 0; j < 8; ++j) { o0[j] = (bf16)ts[cc0 + j][nl]; o1[j] = (bf16)ts[cc0 + 8 + j][nl]; }
  *(v8bf*)dst = o0;
  *(v8bf*)(dst + 8) = o1;
}

// ---------------- K2: pack wall (gate inline) + convert Wo ----------------
__global__ __launch_bounds__(256) void k_pack(
    const float* __restrict__ mpart,
    const float* __restrict__ gw1, const float* __restrict__ gb1,
    const float* __restrict__ gw2, const float* __restrict__ gb2,
    const float* __restrict__ Wq, const float* __restrict__ Wk,
    const float* __restrict__ Wb1, const float* __restrict__ Wb2,
    const float* __restrict__ Wv, const float* __restrict__ Wo,
    bf16* __restrict__ wall, bf16* __restrict__ wo_bf) {
  __shared__ float ms[CH];
  __shared__ float hid[RD];
  const int blk = blockIdx.x;
  const int t = threadIdx.x;
  if (blk >= 768) {                          // Wo f32 -> bf16
    int i = (blk - 768) * 256 + t;
    wo_bf[i] = (bf16)Wo[i];
    return;
  }
  const int b = blk / 384, row = blk % 384;
  float v;
  if (row < 32)       v = Wq[row * CH + t] * LOG2E;
  else if (row < 64) {                       // gate-folded Wk (recompute MLP per block)
    float m = 0.f;
    const float* mp = mpart + (size_t)(b * CH + t) * 64;
    #pragma unroll
    for (int j = 0; j < 64; ++j) m += mp[j];
    ms[t] = m * (1.0f / HW);
    __syncthreads();
    if (t < RD) {
      float a = gb1[t];
      for (int c = 0; c < CH; ++c) a += gw1[t * CH + c] * ms[c];
      hid[t] = fmaxf(a, 0.f);
    }
    __syncthreads();
    float a = gb2[t];
    #pragma unroll
    for (int r = 0; r < RD; ++r) a += gw2[t * RD + r] * hid[r];
    float s = 1.f / (1.f + __expf(-a));
    v = Wk[(row - 32) * CH + t] * s;
  }
  else if (row < 96)  v = Wb1[(row - 64) * CH + t];
  else if (row < 128) v = Wb2[(row - 96) * CH + t];
  else                v = Wv[(row - 128) * CH + t];
  wall[((size_t)b * 384 + row) * CH + t] = (bf16)v;
}

// ---------------- K3: fused 1x1 projections via MFMA ----------------
__global__ __launch_bounds__(256, 4) void k_proj(
    const bf16* __restrict__ xbt, const bf16* __restrict__ wall,
    bf16* __restrict__ qt, bf16* __restrict__ kt,
    bf16* __restrict__ b1r, bf16* __restrict__ b2r, bf16* __restrict__ vt) {
  __shared__ __align__(16) bf16 xs[32][264];
  __shared__ __align__(16) bf16 tr[4][16][24];
  const int blk = blockIdx.x;
  const int b  = blk >> 9;
  const int bm = (blk >> 7) & 3;
  const int nt = blk & 127;
  const int n0 = nt * 32;
  const int t = threadIdx.x;
  {
    const int row = t >> 3, c0 = (t & 7) * 32;
    const bf16* src = xbt + ((size_t)(b * HW + n0 + row)) * CH + c0;
    #pragma unroll
    for (int i = 0; i < 4; ++i)
      *(v8bf*)&xs[row][c0 + i * 8] = *(const v8bf*)(src + i * 8);
  }
  __syncthreads();
  const int w = t >> 6, lane = t & 63, cl = lane & 15, kh = lane >> 4;
  const int nsub = (w & 1) * 16;
  const int otrio = (w >> 1) * 3;
  const v4f vzero = {0.f, 0.f, 0.f, 0.f};
  v4f acc[3] = {vzero, vzero, vzero};
  const bf16* wb = wall + ((size_t)b * 384 + bm * 96) * CH;
  for (int kk = 0; kk < 8; ++kk) {
    v8bf bx = *(const v8bf*)&xs[nsub + cl][kk * 32 + kh * 8];
    #pragma unroll
    for (int j = 0; j < 3; ++j) {
      v8bf af = *(const v8bf*)(wb + (size_t)((otrio + j) * 16 + cl) * CH + kk * 32 + kh * 8);
      acc[j] = __builtin_amdgcn_mfma_f32_16x16x32_bf16(af, bx, acc[j], 0, 0, 0);
    }
  }
  const int n = n0 + nsub + cl;
  #pragma unroll
  for (int j = 0; j < 3; ++j) {
    const int o0 = bm * 96 + (otrio + j) * 16;
    if (o0 < 128) {
      const bool rel = (o0 >= 64);
      v4bf pk;
      #pragma unroll
      for (int r = 0; r < 4; ++r) {
        float v = acc[j][r];
        if (rel) v = fmaxf(v, 0.f);
        pk[r] = (bf16)v;
      }
      const int seg = o0 >> 5;
      bf16* base = seg == 0 ? qt : seg == 1 ? kt : seg == 2 ? b1r : b2r;
      *(v4bf*)&base[((size_t)b * HW + n) * KC + (o0 & 31) + kh * 4] = pk;
    } else {
      #pragma unroll
      for (int r = 0; r < 4; ++r) tr[w][kh * 4 + r][cl] = (bf16)acc[j][r];
      asm volatile("s_waitcnt lgkmcnt(0)" ::: "memory");
      __builtin_amdgcn_sched_barrier(0);
      const int row = lane >> 2, nch = (lane & 3) * 4;
      v4bf d = *(const v4bf*)&tr[w][row][nch];
      *(v4bf*)&vt[((size_t)b * CH + (o0 - 128) + row) * VSTRIDE + n0 + nsub + nch] = d;
    }
  }
}

// ---------------- K3b: 1-D 3-tap pool (-log2e*w_gb/9 folded into bs1) ----------------
__global__ __launch_bounds__(256) void k_pool(const bf16* __restrict__ b1r,
    const bf16* __restrict__ b2r, const float* __restrict__ wgb,
    bf16* __restrict__ bs1, bf16* __restrict__ bs2) {
  int i = blockIdx.x * 256 + threadIdx.x;
  int n = (i >> 5) & (HW - 1);
  float a = (float)b1r[i], c = (float)b2r[i];
  if (n > 0)      { a += (float)b1r[i - KC]; c += (float)b2r[i - KC]; }
  if (n < HW - 1) { a += (float)b1r[i + KC]; c += (float)b2r[i + KC]; }
  const float ws = -LOG2E * wgb[0] * (1.f / 9.f);
  bs1[i] = (bf16)(a * ws);
  bs2[i] = (bf16)c;
}

// ---------------- K4: flash attention — single barrier per step ----------------
// blk = rt*8 + os; 64-row tile, 512-key split, 16 steps of 32 keys.
// QK: wave w computes P rows [w*16,+16) (swapped MFMA, lane-local).
// PV: wave w computes all 64 rows x channels [w*64,+64).
// vbuf is WAVE-PRIVATE (wave w stages/reads only its 64-ch slice) -> no barrier
// needed for V. P (plds) and K/B2 are cross-wave -> double-buffered, ONE
// __syncthreads per step: writes to [pb^1 next-K] and [pb P] before it, reads
// after it. Max wave skew = 1 segment, so buffer reuse 2 steps later is safe
// (every wave passed the intervening barrier after finishing its reads).
__global__ __launch_bounds__(256, 4) void k_attn(
    const bf16* __restrict__ qtg, const bf16* __restrict__ ktg,
    const bf16* __restrict__ bs1g, const bf16* __restrict__ bs2g,
    const bf16* __restrict__ vtg,
    bf16* __restrict__ pacc, float* __restrict__ pl) {
  __shared__ __align__(16) bf16 vbuf[128][64];     // 16 KB, wave-private quarters
  __shared__ __align__(16) bf16 kbuf[2][32][40];   // K dbuf
  __shared__ __align__(16) bf16 bbuf[2][32][40];   // B2 dbuf
  __shared__ __align__(16) bf16 plds[2][64][40];   // P dbuf [qrow][key]
  const int blk = blockIdx.x;
  const int rt  = blk >> 3;
  const int os  = blk & 7;
  const int b   = rt >> 6;
  const int row0 = (rt & 63) * 64;
  const int t = threadIdx.x;
  const int w = t >> 6;
  const int lane = t & 63;
  const int cl = lane & 15, kh = lane >> 4;
  const int kb = os * 512;
  const v4f vzero = {0.f, 0.f, 0.f, 0.f};
  const size_t qoff = ((size_t)(b * HW + row0 + w * 16 + cl)) * KC + kh * 8;
  const v8bf qf  = *(const v8bf*)(qtg + qoff);
  const v8bf b1f = *(const v8bf*)(bs1g + qoff);
  const bf16* kt = ktg + (size_t)b * HW * KC;
  const bf16* b2 = bs2g + (size_t)b * HW * KC;
  const bf16* vt = vtg + (size_t)b * CH * VSTRIDE;
  // K/B2 staging: threads 0-127 -> kbuf, 128-255 -> bbuf (1 v8bf each)
  const int sr = (t >> 2) & 31, sl = (t & 3) * 8;
  const bf16* sbase = (t < 128) ? kt : b2;
  bf16* sd0 = (t < 128) ? &kbuf[0][sr][sl] : &bbuf[0][sr][sl];
  bf16* sd1 = (t < 128) ? &kbuf[1][sr][sl] : &bbuf[1][sr][sl];
  // V staging (wave-private): same swizzle as R10
  const int vsl = lane & 3;
  const int vslot3 = ((((lane >> 2) & 1) * 4 + vsl) ^ (lane >> 3)) * 8;
  const int rline = w * 32 + (cl >> 1);
  const int rslot = ((((cl & 1) * 4) + kh) ^ (cl >> 1)) * 8;

  *(v8bf*)sd0 = *(const v8bf*)(sbase + (size_t)(kb + sr) * KC + sl);
  __syncthreads();

  v4f acc[16];
  #pragma unroll
  for (int f = 0; f < 16; ++f) acc[f] = vzero;
  float psum = 0.f;

  for (int s = 0; s < 16; ++s) {
    const int m0 = kb + s * 32;
    const int pb = s & 1;
    // V reg loads (wave-private channels)
    v8bf vr[4];
    #pragma unroll
    for (int i = 0; i < 4; ++i)
      vr[i] = *(const v8bf*)(vt + (size_t)(w * 64 + i * 16 + (lane >> 2)) * VSTRIDE + m0 + vsl * 8);
    // next K/B2 prefetch
    v8bf pr;
    if (s < 15)
      pr = *(const v8bf*)(sbase + (size_t)(m0 + 32 + sr) * KC + sl);
    // swapped QK from kbuf[pb]: lane owns 8 keys of its own row (w*16+cl)
    #pragma unroll
    for (int cb = 0; cb < 2; ++cb) {
      v8bf kf  = *(const v8bf*)&kbuf[pb][cb * 16 + cl][kh * 8];
      v8bf b2f = *(const v8bf*)&bbuf[pb][cb * 16 + cl][kh * 8];
      v4f sim = __builtin_amdgcn_mfma_f32_16x16x32_bf16(kf,  qf,  vzero, 0, 0, 0);
      v4f bia = __builtin_amdgcn_mfma_f32_16x16x32_bf16(b2f, b1f, vzero, 0, 0, 0);
      v4bf pk;
      #pragma unroll
      for (int r = 0; r < 4; ++r) {
        float bm = frcp(1.f + fexp2(bia[r]));   // sigmoid (-log2e folded in bs1)
        float pv = fexp2(sim[r] * bm);          // exp (log2e folded in qt)
        psum += pv;
        pk[r] = (bf16)pv;
      }
      *(v4bf*)&plds[pb][w * 16 + cl][cb * 16 + kh * 4] = pk;
    }
    // stage V into own quarter (ordering vs PV read: barrier's lgkm drain)
    #pragma unroll
    for (int i = 0; i < 4; ++i)
      *(v8bf*)&vbuf[w * 32 + i * 8 + (lane >> 3)][vslot3] = vr[i];
    // stage next K/B2 into the other buffer
    if (s < 15) {
      bf16* sd = pb ? sd0 : sd1;
      *(v8bf*)sd = pr;
    }
    __syncthreads();                            // ONE barrier: P[pb], K[pb^1], own V
    // PV: all 64 rows x my 64-ch slice
    v8bf vf[4], pa[4];
    #pragma unroll
    for (int f = 0; f < 4; ++f)
      vf[f] = *(const v8bf*)&vbuf[rline + f * 8][rslot];
    #pragma unroll
    for (int rg = 0; rg < 4; ++rg)
      pa[rg] = *(const v8bf*)&plds[pb][rg * 16 + cl][kh * 8];
    #pragma unroll
    for (int rg = 0; rg < 4; ++rg)
      #pragma unroll
      for (int f = 0; f < 4; ++f)
        acc[rg * 4 + f] = __builtin_amdgcn_mfma_f32_16x16x32_bf16(pa[rg], vf[f], acc[rg * 4 + f], 0, 0, 0);
  }
  __syncthreads();   // all PV vbuf reads done before epilogue reuses vbuf as scratch

  // ---- epilogue ----
  {
    float s2 = psum;
    s2 += __shfl_xor(s2, 16);
    s2 += __shfl_xor(s2, 32);
    if (kh == 0) pl[blk * 64 + w * 16 + cl] = s2;
  }
  bf16 (*ep)[64] = (bf16 (*)[64])vbuf;
  bf16* po = pacc + (size_t)blk * 64 * CH;
  for (int rg = 0; rg < 4; ++rg) {
    #pragma unroll
    for (int f = 0; f < 4; ++f)
      #pragma unroll
      for (int r = 0; r < 4; ++r)
        ep[w * 16 + kh * 4 + r][f * 16 + cl] = (bf16)acc[rg * 4 + f][r];
    asm volatile("s_waitcnt lgkmcnt(0)" ::: "memory");
    __builtin_amdgcn_sched_barrier(0);
    #pragma unroll
    for (int it = 0; it < 2; ++it) {
      int row = lane >> 2, chunk = it * 4 + (lane & 3);
      v8bf d = *(const v8bf*)&ep[w * 16 + row][chunk * 8];
      *(v8bf*)&po[(size_t)(rg * 16 + row) * CH + w * 64 + chunk * 8] = d;
    }
  }
}

// ---------------- K5: fused combine (coalesced) + 1x1 conv + BN + ReLU + residual ---
// Phase 1: coalesced split-K sum (thread <-> (row, 16-ch chunk)) -> LDS bf16 tile.
// Phase 2: MFMA with A-frags from LDS (264-pad -> 2-way banks, free).
__global__ __launch_bounds__(256) void k_outc(
    const bf16* __restrict__ pacc, const float* __restrict__ pl,
    const bf16* __restrict__ wo,
    const float* __restrict__ bns, const float* __restrict__ bnb,
    const float* __restrict__ bnm, const float* __restrict__ bnv,
    const float* __restrict__ gamma, const float* __restrict__ x,
    float* __restrict__ out) {
  __shared__ __align__(16) bf16 cs[16][264];
  const int blk = blockIdx.x;                  // 512
  const int n0g = blk * 16;
  const int b   = n0g >> 12;
  const int n0  = n0g & (HW - 1);
  const int t = threadIdx.x;
  const int base = (blk >> 2) * 8;
  // ---- phase 1: combine (coalesced) ----
  {
    const int r16 = t >> 4;                    // 0..15
    const int ch0 = (t & 15) * 16;
    const int rl = (blk & 3) * 16 + r16;
    float den = 0.f;
    #pragma unroll
    for (int s = 0; s < 8; ++s) den += pl[(base + s) * 64 + rl];
    const float inv = 1.f / den;
    float sum[16];
    #pragma unroll
    for (int j = 0; j < 16; ++j) sum[j] = 0.f;
    #pragma unroll
    for (int s = 0; s < 8; ++s) {
      const bf16* pp = &pacc[((size_t)(base + s) * 64 + rl) * CH + ch0];
      v8bf p0 = *(const v8bf*)pp;
      v8bf p1 = *(const v8bf*)(pp + 8);
      #pragma unroll
      for (int j = 0; j < 8; ++j) { sum[j] += (float)p0[j]; sum[8 + j] += (float)p1[j]; }
    }
    v8bf o0, o1;
    #pragma unroll
    for (int j = 0; j < 8; ++j) {
      o0[j] = (bf16)(sum[j] * inv);
      o1[j] = (bf16)(sum[8 + j] * inv);
    }
    *(v8bf*)&cs[r16][ch0] = o0;
    *(v8bf*)&cs[r16][ch0 + 8] = o1;
  }
  __syncthreads();
  // ---- phase 2: MFMA ----
  const int w = t >> 6, lane = t & 63, cl = lane & 15, kh = lane >> 4;
  const v4f vzero = {0.f, 0.f, 0.f, 0.f};
  v8bf a[8];
  #pragma unroll
  for (int kk = 0; kk < 8; ++kk)
    a[kk] = *(const v8bf*)&cs[cl][kk * 32 + kh * 8];
  v4f acc[4] = {vzero, vzero, vzero, vzero};
  #pragma unroll
  for (int kk = 0; kk < 8; ++kk)
    #pragma unroll
    for (int cg = 0; cg < 4; ++cg) {
      v8bf bfr = *(const v8bf*)(wo + (size_t)(w * 64 + cg * 16 + cl) * CH + kk * 32 + kh * 8);
      acc[cg] = __builtin_amdgcn_mfma_f32_16x16x32_bf16(a[kk], bfr, acc[cg], 0, 0, 0);
    }
  const float g = gamma[0];
  #pragma unroll
  for (int cg = 0; cg < 4; ++cg) {
    int o = w * 64 + cg * 16 + cl;
    float isc = bns[o] / sqrtf(bnv[o] + BNEPS);
    float mu = bnm[o], bb = bnb[o];
    size_t oi = ((size_t)b * CH + o) * HW + n0 + kh * 4;
    v4f xv = *(const v4f*)&x[oi];
    v4f ov;
    #pragma unroll
    for (int r = 0; r < 4; ++r) {
      float v = (acc[cg][r] - mu) * isc + bb;
      v = fmaxf(v, 0.f);
      ov[r] = g * v + xv[r];
    }
    *(v4f*)&out[oi] = ov;
  }
}

// ---------------- launch ----------------
extern "C" void kernel_launch(void* const* d_in, const int* in_sizes, int n_in,
                              void* d_out, int out_size, void* d_ws, size_t ws_size,
                              hipStream_t stream) {
  const float* x    = (const float*)d_in[0];
  const float* Wq   = (const float*)d_in[1];
  const float* Wk   = (const float*)d_in[2];
  const float* Wv   = (const float*)d_in[3];
  const float* Wb1  = (const float*)d_in[4];
  const float* Wb2  = (const float*)d_in[5];
  const float* wgb  = (const float*)d_in[6];
  const float* gw1  = (const float*)d_in[7];
  const float* gb1  = (const float*)d_in[8];
  const float* gw2  = (const float*)d_in[9];
  const float* gb2  = (const float*)d_in[10];
  const float* Wo   = (const float*)d_in[11];
  const float* bns  = (const float*)d_in[12];
  const float* bnb  = (const float*)d_in[13];
  const float* bnm  = (const float*)d_in[14];
  const float* bnv  = (const float*)d_in[15];
  const float* gam  = (const float*)d_in[16];

  char* ws = (char*)d_ws;
  bf16* qt    = (bf16*)(ws + OFF_QT);
  bf16* kt    = (bf16*)(ws + OFF_KT);
  bf16* bs1   = (bf16*)(ws + OFF_BS1);
  bf16* bs2   = (bf16*)(ws + OFF_BS2);
  bf16* vt    = (bf16*)(ws + OFF_VT);
  bf16* b1r   = (bf16*)(ws + OFF_B1R);
  bf16* b2r   = (bf16*)(ws + OFF_B2R);
  bf16* pacc  = (bf16*)(ws + OFF_PACC);
  float* plv  = (float*)(ws + OFF_PL);
  bf16* wobf  = (bf16*)(ws + OFF_WOBF);
  bf16* xbt   = (bf16*)(ws + OFF_XBT);
  bf16* wall  = (bf16*)(ws + OFF_WALL);
  float* mprt = (float*)(ws + OFF_MPART);
  float* out  = (float*)d_out;

  hipLaunchKernelGGL(k_prep, dim3(512),  dim3(256), 0, stream, x, xbt, mprt);
  hipLaunchKernelGGL(k_pack, dim3(1024), dim3(256), 0, stream, mprt, gw1, gb1, gw2, gb2,
                     Wq, Wk, Wb1, Wb2, Wv, Wo, wall, wobf);
  hipLaunchKernelGGL(k_proj, dim3(1024), dim3(256), 0, stream, xbt, wall, qt, kt, b1r, b2r, vt);
  hipLaunchKernelGGL(k_pool, dim3(NB * HW * KC / 256), dim3(256), 0, stream, b1r, b2r, wgb, bs1, bs2);
  hipLaunchKernelGGL(k_attn, dim3(1024), dim3(256), 0, stream, qt, kt, bs1, bs2, vt, pacc, plv);
  hipLaunchKernelGGL(k_outc, dim3(512),  dim3(256), 0, stream, pacc, plv, wobf, bns, bnb, bnm, bnv, gam, x, out);
}